// Round 5
// baseline (164.108 us; speedup 1.0000x reference)
//
#include <hip/hip_runtime.h>
#include <stdint.h>

typedef unsigned long long ull;

#define NUM_CLASSES 21
#define NFG 20
#define TOPK 200
#define KPRE 256
#define BS 512                   // nms block size (8 waves)
#define NV2 18                   // ceil(8732/512)
#define CONF_TH 0.01f
#define NMS_TH 0.45f
#define VAR0 0.1f
#define VAR1 0.2f
#define BITS_CONF 0x3C23D70Au    // __float_as_uint(0.01f)
#define BITS_ONE1 0x3F800001u    // just above 1.0f (softmax <= 1)

// Kernel 1: grid (chunks-of-256-priors, images). float4 staging in, softmax,
// LDS transpose, float4 stores out. probs layout: [B][NFG][P]. (unchanged)
__global__ __launch_bounds__(256) void softmax_probs_kernel(
    const float* __restrict__ conf, float* __restrict__ probs, int P) {
    __shared__ __align__(16) float buf[256 * NUM_CLASSES];
    __shared__ __align__(16) float obuf[NFG * 256];
    const int t = threadIdx.x;
    const int b = blockIdx.y;
    const int p0 = blockIdx.x << 8;
    const int cnt = min(256, P - p0);
    const float* src = conf + ((size_t)b * P + p0) * NUM_CLASSES;

    if (cnt == 256) {
        const float4* s4 = (const float4*)src;
        float4* b4 = (float4*)buf;
#pragma unroll
        for (int k = 0; k < 6; ++k) {
            int i = (k << 8) + t;
            if (i < (256 * NUM_CLASSES) / 4) b4[i] = s4[i];
        }
    } else {
        int n = cnt * NUM_CLASSES;
        for (int i = t; i < n; i += 256) buf[i] = src[i];
    }
    __syncthreads();

    if (t < cnt) {
        const float* row = buf + t * NUM_CLASSES;
        float x[NUM_CLASSES];
        float mx = row[0];
        x[0] = mx;
#pragma unroll
        for (int j = 1; j < NUM_CLASSES; ++j) { x[j] = row[j]; mx = fmaxf(mx, x[j]); }
        float s = 0.f;
#pragma unroll
        for (int j = 0; j < NUM_CLASSES; ++j) { x[j] = expf(x[j] - mx); s += x[j]; }
#pragma unroll
        for (int c = 1; c < NUM_CLASSES; ++c)
            obuf[(c - 1) * 256 + t] = x[c] / s;     // true div: match ref ulps
    }
    __syncthreads();

    float* dst = probs + ((size_t)b * NFG) * P + p0;
    if (cnt == 256) {
#pragma unroll
        for (int k = 0; k < 5; ++k) {
            int e = (k << 8) + t;
            int c = e >> 6;
            int f = e & 63;
            float4 val = ((const float4*)obuf)[(c << 6) + f];
            *(float4*)(dst + (size_t)c * P + (f << 2)) = val;
        }
    } else {
        for (int e = t; e < NFG * cnt; e += 256) {
            int c = e / cnt;
            int f = e - c * cnt;
            dst[(size_t)c * P + f] = obuf[c * 256 + f];
        }
    }
}

// Kernel 2: one 512-thread block per (b, fg_class).
__global__ __launch_bounds__(BS) void nms_topk_kernel(
    const float* __restrict__ probs, const float* __restrict__ loc,
    const float* __restrict__ prior, float* __restrict__ out, int B, int P) {

    __shared__ ull arr[2 * KPRE];        // 4 KB
    __shared__ int wsum[2][8][4];
    __shared__ int s_cnt;
    __shared__ float4 sbox[KPRE];        // 4 KB
    __shared__ float sarea[KPRE];        // 1 KB
    __shared__ ull smask[4][KPRE];       // 8 KB, transposed: [tile][row] -> 8B stride, conflict-free
    __shared__ ull kept[4];
    __shared__ int s_chg[2];

    const int t = threadIdx.x;
    const int lane = t & 63;
    const int wid = t >> 6;              // 0..7
    const ull lmask_lt = (1ULL << lane) - 1ULL;
    const int pair = blockIdx.x;         // b*NFG + c
    const int b = pair / NFG;
    const float* sp = probs + (size_t)pair * P;

    // A: scores into registers (compile-time trip count => VGPRs, no spill)
    unsigned int ubits[NV2];
#pragma unroll
    for (int i = 0; i < NV2; ++i) {
        int p = i * BS + t;
        ubits[i] = (p < P) ? __float_as_uint(sp[p]) : 0u;
    }
    if (t == 0) { s_cnt = 0; s_chg[0] = 0; s_chg[1] = 0; }

    // B: largest T in [0.01, 1.0] with count(bits >= T) >= 256; 2 bits/iter.
    unsigned int lo = BITS_CONF, hi = BITS_ONE1;
    int it = 0;
    while (hi - lo > 1u) {
        unsigned int d = hi - lo;
        unsigned int m1, m2, m3;
        if (d >= 4u) { unsigned int q = d >> 2; m1 = lo + q; m2 = lo + 2 * q; m3 = lo + 3 * q; }
        else { m1 = m2 = m3 = lo + (d >> 1); }
        int c1 = 0, c2 = 0, c3 = 0;
#pragma unroll
        for (int i = 0; i < NV2; ++i) {
            unsigned int u = ubits[i];
            c1 += (u >= m1) ? 1 : 0;
            c2 += (u >= m2) ? 1 : 0;
            c3 += (u >= m3) ? 1 : 0;
        }
#pragma unroll
        for (int off = 32; off > 0; off >>= 1) {
            c1 += __shfl_down(c1, off);
            c2 += __shfl_down(c2, off);
            c3 += __shfl_down(c3, off);
        }
        if (lane == 0) {
            wsum[it & 1][wid][0] = c1; wsum[it & 1][wid][1] = c2; wsum[it & 1][wid][2] = c3;
        }
        __syncthreads();
        int t1 = 0, t2 = 0, t3 = 0;
#pragma unroll
        for (int w = 0; w < 8; ++w) {
            t1 += wsum[it & 1][w][0]; t2 += wsum[it & 1][w][1]; t3 += wsum[it & 1][w][2];
        }
        if (t3 >= KPRE) lo = m3;
        else if (t2 >= KPRE) { lo = m2; hi = m3; }
        else if (t1 >= KPRE) { lo = m1; hi = m2; }
        else hi = m1;
        ++it;
    }
    const unsigned int T = lo;

    // C: ballot-compaction gather (cap 512)
    int wtot = 0;
#pragma unroll
    for (int i = 0; i < NV2; ++i) {
        int p = i * BS + t;
        bool pred = (p < P) && (ubits[i] >= T);
        wtot += __popcll(__ballot(pred));
    }
    int wbase = 0;
    if (lane == 0) wbase = atomicAdd(&s_cnt, wtot);
    wbase = __shfl(wbase, 0);
    int run = wbase;
#pragma unroll
    for (int i = 0; i < NV2; ++i) {
        int p = i * BS + t;
        bool pred = (p < P) && (ubits[i] >= T);
        ull bal = __ballot(pred);
        if (pred) {
            int slot = run + __popcll(bal & lmask_lt);
            if (slot < 2 * KPRE)
                arr[slot] = ((ull)ubits[i] << 32) | (unsigned int)(~p);
        }
        run += __popcll(bal);
    }
    __syncthreads();
    const int nval = min(s_cnt, 2 * KPRE);
    if (t >= nval && t < 2 * KPRE) arr[t] = 0ULL;
    __syncthreads();

    // D: sort descending; key = (bits<<32)|~idx => value desc, index asc (JAX)
    ull key = 0ULL;
    if (nval <= KPRE) {
        if (t < KPRE) key = arr[t];
        for (int kk = 2; kk <= KPRE; kk <<= 1) {
            for (int j = kk >> 1; j > 0; j >>= 1) {
                if (j >= 64) {
                    if (t < KPRE) arr[t] = key;
                    __syncthreads();
                    ull other = (t < KPRE) ? arr[t ^ j] : 0ULL;
                    __syncthreads();
                    if (t < KPRE) {
                        bool dirDesc = ((t & kk) == 0);
                        bool amLow = ((t & j) == 0);
                        ull mx = (key > other) ? key : other;
                        ull mn = (key > other) ? other : key;
                        key = (dirDesc == amLow) ? mx : mn;
                    }
                } else {
                    if (t < KPRE) {
                        ull other = __shfl_xor(key, j);
                        bool dirDesc = ((t & kk) == 0);
                        bool amLow = ((t & j) == 0);
                        ull mx = (key > other) ? key : other;
                        ull mn = (key > other) ? other : key;
                        key = (dirDesc == amLow) ? mx : mn;
                    }
                }
            }
        }
    } else {
        // rare tie-overflow path: 512-element LDS bitonic, one element/thread
        for (int kk = 2; kk <= 2 * KPRE; kk <<= 1) {
            for (int j = kk >> 1; j > 0; j >>= 1) {
                ull a = arr[t];
                ull p2 = arr[t ^ j];
                __syncthreads();
                bool dirDesc = ((t & kk) == 0);
                bool amLow = ((t & j) == 0);
                ull mx = (a > p2) ? a : p2;
                ull mn = (a > p2) ? p2 : a;
                arr[t] = (dirDesc == amLow) ? mx : mn;
                __syncthreads();
            }
        }
        if (t < KPRE) key = arr[t];
    }

    // E: decode candidate t (t < 256)
    float v = 0.f, x1 = 0.f, y1 = 0.f, x2 = 0.f, y2 = 0.f;
    if (t < KPRE) {
        v = __uint_as_float((unsigned int)(key >> 32));
        int idx = (int)(~(unsigned int)(key & 0xFFFFFFFFu));
        if (idx < 0 || idx >= P) { idx = 0; v = 0.f; }
        const float4 lv = *(const float4*)(loc + ((size_t)b * P + idx) * 4);
        const float4 pv = *(const float4*)(prior + (size_t)idx * 4);
        float cx = pv.x + (lv.x * VAR0) * pv.z;
        float cy = pv.y + (lv.y * VAR0) * pv.w;
        float w = pv.z * expf(lv.z * VAR1);
        float h = pv.w * expf(lv.w * VAR1);
        x1 = cx - w * 0.5f;
        y1 = cy - h * 0.5f;
        x2 = x1 + w;
        y2 = y1 + h;
        sbox[t] = make_float4(x1, y1, x2, y2);
        sarea[t] = fmaxf(x2 - x1, 0.f) * fmaxf(y2 - y1, 0.f);
    }
    __syncthreads();

    // F1: candidate-centric mask build. Thread handles row r = t&255, g-range
    // halves split across the two 256-thread groups. sbox[g]/sarea[g] are the
    // SAME address across all lanes => LDS broadcast (free). smask [tile][row]
    // layout => natural 8B stride, conflict-free.
    {
        const int r = t & (KPRE - 1);
        const int gbase = (t >> 8) << 7;        // 0 or 128
        const float4 rb = sbox[r];
        const float ra = sarea[r];
        ull mm0 = 0ULL, mm1 = 0ULL;
#pragma unroll 1
        for (int ii = 0; ii < 64; ++ii) {
            int g = gbase + ii;
            float4 gb = sbox[g];
            float lx = fmaxf(gb.x, rb.x), ly = fmaxf(gb.y, rb.y);
            float rx = fminf(gb.z, rb.z), ry = fminf(gb.w, rb.w);
            float inter = fmaxf(rx - lx, 0.f) * fmaxf(ry - ly, 0.f);
            bool s = false;
            if (inter > 0.f) {   // skip exact IEEE div for the ~99% disjoint pairs
                float uni = sarea[g] + ra - inter;
                s = (inter / fmaxf(uni, 1e-9f)) > NMS_TH;
            }
            mm0 |= ((ull)(s ? 1u : 0u)) << ii;
        }
#pragma unroll 1
        for (int ii = 0; ii < 64; ++ii) {
            int g = gbase + 64 + ii;
            float4 gb = sbox[g];
            float lx = fmaxf(gb.x, rb.x), ly = fmaxf(gb.y, rb.y);
            float rx = fminf(gb.z, rb.z), ry = fminf(gb.w, rb.w);
            float inter = fmaxf(rx - lx, 0.f) * fmaxf(ry - ly, 0.f);
            bool s = false;
            if (inter > 0.f) {
                float uni = sarea[g] + ra - inter;
                s = (inter / fmaxf(uni, 1e-9f)) > NMS_TH;
            }
            mm1 |= ((ull)(s ? 1u : 0u)) << ii;
        }
        int tb = (t >> 8) << 1;                 // tiles {0,1} or {2,3}
        smask[tb][r] = mm0;
        smask[tb + 1][r] = mm1;
    }
    __syncthreads();

    // F2: Jacobi fixed-point resolution (converges to exact sequential NMS;
    // prefix-induction: >=1 more row finalized per iter, typically ~3 iters).
    ull m0 = 0, m1 = 0, m2 = 0, m3 = 0;
    int valid = 0, alive = 0;
    if (t < KPRE) {
        m0 = smask[0][t]; m1 = smask[1][t]; m2 = smask[2][t]; m3 = smask[3][t];
        if (wid == 0)      { m0 &= lmask_lt; m1 = 0; m2 = 0; m3 = 0; }
        else if (wid == 1) { m1 &= lmask_lt; m2 = 0; m3 = 0; }
        else if (wid == 2) { m2 &= lmask_lt; m3 = 0; }
        else               { m3 &= lmask_lt; }
        valid = (v > CONF_TH) ? 1 : 0;
        alive = valid;
        ull km = __ballot(valid != 0);
        if (lane == 0) kept[wid] = km;
    }
    __syncthreads();
    for (int iter = 0; iter < KPRE; ++iter) {
        ull K0 = kept[0], K1 = kept[1], K2 = kept[2], K3 = kept[3];
        __syncthreads();                        // all reads before any write
        if (t < KPRE) {
            ull dead = (m0 & K0) | (m1 & K1) | (m2 & K2) | (m3 & K3);
            alive = (valid && dead == 0ULL) ? 1 : 0;
            ull km = __ballot(alive != 0);
            ull oldk = (wid == 0) ? K0 : (wid == 1) ? K1 : (wid == 2) ? K2 : K3;
            if (lane == 0 && km != oldk) { kept[wid] = km; s_chg[iter & 1] = 1; }
        }
        if (t == 0) s_chg[(iter & 1) ^ 1] = 0;  // reset other slot for next iter
        __syncthreads();
        if (s_chg[iter & 1] == 0) break;
    }

    // G: rank via popcounts, write kept rows + zero-fill
    if (t < KPRE) {
        ull K0 = kept[0], K1 = kept[1], K2 = kept[2], K3 = kept[3];
        int rank = 0;
        if (wid > 0) rank += __popcll(K0);
        if (wid > 1) rank += __popcll(K1);
        if (wid > 2) rank += __popcll(K2);
        ull ownk = (wid == 0) ? K0 : (wid == 1) ? K1 : (wid == 2) ? K2 : K3;
        rank += __popcll(ownk & lmask_lt);
        int total = __popcll(K0) + __popcll(K1) + __popcll(K2) + __popcll(K3);

        float* orow = out + (size_t)pair * TOPK * 5;
        if (alive && rank < TOPK) {
            float* o = orow + rank * 5;
            o[0] = v; o[1] = x1; o[2] = y1; o[3] = x2; o[4] = y2;
        }
        if (t < TOPK && t >= total) {
            float* o = orow + t * 5;
            o[0] = 0.f; o[1] = 0.f; o[2] = 0.f; o[3] = 0.f; o[4] = 0.f;
        }
    }
}

extern "C" void kernel_launch(void* const* d_in, const int* in_sizes, int n_in,
                              void* d_out, int out_size, void* d_ws, size_t ws_size,
                              hipStream_t stream) {
    const float* loc = (const float*)d_in[0];
    const float* conf = (const float*)d_in[1];
    const float* prior = (const float*)d_in[2];
    float* out = (float*)d_out;
    float* probs = (float*)d_ws;            // [B][NFG][P] floats = 22.35 MB

    int P = in_sizes[2] / 4;                // 8732
    int B = in_sizes[0] / (4 * P);          // 32

    dim3 g1((P + 255) / 256, B);
    softmax_probs_kernel<<<g1, 256, 0, stream>>>(conf, probs, P);
    nms_topk_kernel<<<B * NFG, BS, 0, stream>>>(probs, loc, prior, out, B, P);
}